// Round 4
// baseline (504.879 us; speedup 1.0000x reference)
//
#include <hip/hip_runtime.h>
#include <math.h>

constexpr float WLIM = 5000.0f;
constexpr double RIDGE = 1e-7;

#define GBLK 256          // blocks in hist/scatter passes
#define MAXNB 1024        // max buckets (supports nN up to 131072)

// ---------------- Kernel 1: per-block bucket histogram (LDS atomics only) ----------------
__global__ __launch_bounds__(1024) void k_hist(const int* __restrict__ row,
                                               int* __restrict__ table,
                                               int nE, int CE, int NB) {
    __shared__ int h[MAXNB];
    const int g = blockIdx.x, tid = threadIdx.x;
    for (int i = tid; i < NB; i += 1024) h[i] = 0;
    __syncthreads();
    int s = g * CE;
    int e_end = min(s + CE, nE);
    for (int i = s + tid; i < e_end; i += 1024)
        atomicAdd(&h[row[i] >> 7], 1);
    __syncthreads();
    for (int i = tid; i < NB; i += 1024) table[(size_t)g * NB + i] = h[i];
}

// ---------------- Kernel 2: scan -> per-(bucket,block) start offsets + bucket bases ----
__global__ __launch_bounds__(1024) void k_scan(int* __restrict__ table,
                                               int* __restrict__ base,
                                               int NB, int G) {
    __shared__ int tot[MAXNB];
    const int b = threadIdx.x;
    int myTot = 0;
    if (b < NB) {
        int s = 0;
        for (int g = 0; g < G; ++g) {
            int idx = g * NB + b;         // consecutive b -> coalesced
            int v = table[idx];
            table[idx] = s;
            s += v;
        }
        myTot = s;
        tot[b] = s;
    }
    __syncthreads();
    // Hillis-Steele inclusive scan of tot[0..NB)
    for (int d = 1; d < MAXNB; d <<= 1) {
        int v = 0;
        if (b >= d && b < NB) v = tot[b - d];
        __syncthreads();
        if (b >= d && b < NB) tot[b] += v;
        __syncthreads();
    }
    if (b < NB) {
        int excl = tot[b] - myTot;
        base[b] = excl;
        if (b == NB - 1) base[NB] = tot[b];
        for (int g = 0; g < G; ++g) table[g * NB + b] += excl;
    }
}

// ---------------- Kernel 3: scatter packed (local_r, col) into bucket order ----------------
// cursors live in LDS (fast int atomics); writes are plain cached stores.
__global__ __launch_bounds__(1024) void k_scatter(const int* __restrict__ row,
                                                  const int* __restrict__ col,
                                                  const int* __restrict__ table,
                                                  unsigned int* __restrict__ sorted,
                                                  int nE, int CE, int NB) {
    __shared__ int cur[MAXNB];
    const int g = blockIdx.x, tid = threadIdx.x;
    for (int i = tid; i < NB; i += 1024) cur[i] = table[(size_t)g * NB + i];
    __syncthreads();
    int s = g * CE;
    int e_end = min(s + CE, nE);
    for (int i = s + tid; i < e_end; i += 1024) {
        int r = row[i];
        int c = col[i];
        int b = r >> 7;
        int p = atomicAdd(&cur[b], 1);
        sorted[p] = ((unsigned)(r & 127) << 17) | (unsigned)c;  // c < 131072
    }
}

// ---------------- Kernel 4: per-bucket moment accumulation (LDS f32 atomics) + Cholesky ----
__global__ __launch_bounds__(256) void k_nodeb(const float2* __restrict__ pos,
                                               const unsigned int* __restrict__ sorted,
                                               const int* __restrict__ base,
                                               float* __restrict__ C, int nN) {
    __shared__ float macc[128 * 15];
    const int b = blockIdx.x, tid = threadIdx.x;
    for (int i = tid; i < 128 * 15; i += 256) macc[i] = 0.0f;
    __syncthreads();
    int s = base[b], e = base[b + 1];
    for (int i = s + tid; i < e; i += 256) {
        unsigned v = sorted[i];
        int c = (int)(v & 0x1FFFFu);
        int lr = (int)(v >> 17);
        float2 pc = pos[c];
        float2 pr = pos[(b << 7) + lr];
        float x = pc.x - pr.x;
        float y = pc.y - pr.y;
        float xy = x * y, xx = x * x, yy = y * y;
        float* mb = &macc[lr * 15];
        atomicAdd(&mb[0],  x * x);   atomicAdd(&mb[1],  x * y);   atomicAdd(&mb[2],  x * xy);
        atomicAdd(&mb[3],  x * xx);  atomicAdd(&mb[4],  x * yy);
        atomicAdd(&mb[5],  y * y);   atomicAdd(&mb[6],  y * xy);  atomicAdd(&mb[7],  y * xx);
        atomicAdd(&mb[8],  y * yy);
        atomicAdd(&mb[9],  xy * xy); atomicAdd(&mb[10], xy * xx); atomicAdd(&mb[11], xy * yy);
        atomicAdd(&mb[12], xx * xx); atomicAdd(&mb[13], xx * yy);
        atomicAdd(&mb[14], yy * yy);
    }
    __syncthreads();
    if (tid < 128) {
        int n = (b << 7) + tid;
        if (n < nN) {
            double A[5][5];
            {
                const float* mb = &macc[tid * 15];
                int idx = 0;
                #pragma unroll
                for (int i = 0; i < 5; ++i) {
                    #pragma unroll
                    for (int j = i; j < 5; ++j) {
                        double v = (double)mb[idx++];
                        A[i][j] = v;
                        A[j][i] = v;
                    }
                }
            }
            #pragma unroll
            for (int i = 0; i < 5; ++i) A[i][i] += RIDGE;

            // Cholesky (static indices only)
            #pragma unroll
            for (int k = 0; k < 5; ++k) {
                double d = A[k][k];
                d = sqrt(fmax(d, 1e-300));
                A[k][k] = d;
                double inv = 1.0 / d;
                #pragma unroll
                for (int i = k + 1; i < 5; ++i) A[i][k] *= inv;
                #pragma unroll
                for (int j = k + 1; j < 5; ++j) {
                    #pragma unroll
                    for (int i = j; i < 5; ++i) A[i][j] -= A[i][k] * A[j][k];
                }
            }
            double bb[5] = {0.0, 0.0, 0.0, 2.0, 2.0};
            double y[5];
            #pragma unroll
            for (int i = 0; i < 5; ++i) {
                double sv = bb[i];
                #pragma unroll
                for (int k = 0; k < 5; ++k) {
                    if (k < i) sv -= A[i][k] * y[k];
                }
                y[i] = sv / A[i][i];
            }
            double xs[5];
            #pragma unroll
            for (int ii = 4; ii >= 0; --ii) {
                double sv = y[ii];
                #pragma unroll
                for (int k = 0; k < 5; ++k) {
                    if (k > ii) sv -= A[k][ii] * xs[k];
                }
                xs[ii] = sv / A[ii][ii];
            }
            float* cbase = C + (size_t)n * 8;
            #pragma unroll
            for (int i = 0; i < 5; ++i) cbase[i] = (float)xs[i];
            #pragma unroll
            for (int i = 5; i < 8; ++i) cbase[i] = 0.0f;
        }
    }
}

// ---------------- Kernel 5: per-edge weight = <C[row], H>, clipped (overwrites d_out) ----
__global__ __launch_bounds__(256) void k_weights(const float2* __restrict__ pos,
                                                 const int* __restrict__ row,
                                                 const int* __restrict__ col,
                                                 const float* __restrict__ C,
                                                 float* __restrict__ out,
                                                 int nE) {
    int e = blockIdx.x * blockDim.x + threadIdx.x;
    if (e >= nE) return;
    int r = row[e];
    int c = col[e];
    float2 pc = pos[c];
    float2 pr = pos[r];
    float x = pc.x - pr.x;
    float y = pc.y - pr.y;
    const float4* cq = (const float4*)(C + (size_t)r * 8);
    float4 c0 = cq[0];
    float c4 = C[(size_t)r * 8 + 4];
    float w = c0.x * x + c0.y * y + c0.z * (x * y) + c0.w * (x * x) + c4 * (y * y);
    w = fminf(fmaxf(w, -WLIM), WLIM);
    out[e] = w;
}

extern "C" void kernel_launch(void* const* d_in, const int* in_sizes, int n_in,
                              void* d_out, int out_size, void* d_ws, size_t ws_size,
                              hipStream_t stream) {
    const float2* pos = (const float2*)d_in[0];
    const int* ei = (const int*)d_in[1];
    const int nN = in_sizes[0] / 2;   // (N,2) f32
    const int nE = in_sizes[1] / 2;   // (2,E) int32
    const int* row = ei;
    const int* col = ei + nE;

    const int NB = (nN + 127) >> 7;               // buckets of 128 nodes (782)
    const int CE = (nE + GBLK - 1) / GBLK;        // edges per hist/scatter block

    // ws layout: table[GBLK*NB] | base[NB+1] | pad | C[nN*8] (16B-aligned)
    int* table = (int*)d_ws;
    int* base = table + (size_t)GBLK * NB;
    size_t coff = (((size_t)GBLK * NB + NB + 1) + 3) & ~(size_t)3;
    float* C = (float*)((int*)d_ws + coff);

    unsigned int* sorted = (unsigned int*)d_out;  // consumed by k_nodeb before k_weights overwrites
    float* out = (float*)d_out;

    k_hist<<<GBLK, 1024, 0, stream>>>(row, table, nE, CE, NB);
    k_scan<<<1, 1024, 0, stream>>>(table, base, NB, GBLK);
    k_scatter<<<GBLK, 1024, 0, stream>>>(row, col, table, sorted, nE, CE, NB);
    k_nodeb<<<NB, 256, 0, stream>>>(pos, sorted, base, C, nN);
    k_weights<<<(nE + 255) / 256, 256, 0, stream>>>(pos, row, col, C, out, nE);
}

// Round 5
// 277.303 us; speedup vs baseline: 1.8207x; 1.8207x over previous
//
#include <hip/hip_runtime.h>
#include <math.h>

constexpr float WLIM = 5000.0f;
constexpr double RIDGE = 1e-7;

// ---------------- Kernel 1: build per-node linked lists of edges ----------------
// head[r] = last edge seen with row r; next[e] = previous head. next stores COALESCED.
// 4 edges per thread via int4 loads. Atomic count (the wall) unchanged.
__global__ __launch_bounds__(256) void k_build(const int* __restrict__ row,
                                               int* __restrict__ head,
                                               int* __restrict__ nxt, int nE4, int nE) {
    int t = blockIdx.x * blockDim.x + threadIdx.x;
    if (t < nE4) {
        int4 r4 = ((const int4*)row)[t];
        int e0 = t * 4;
        int4 n4;
        n4.x = atomicExch(&head[r4.x], e0 + 0);
        n4.y = atomicExch(&head[r4.y], e0 + 1);
        n4.z = atomicExch(&head[r4.z], e0 + 2);
        n4.w = atomicExch(&head[r4.w], e0 + 3);
        ((int4*)nxt)[t] = n4;
    }
    // scalar tail
    int tail0 = nE4 * 4;
    int i = tail0 + t;
    if (t < (nE - tail0)) {
        int r = row[i];
        int old = atomicExch(&head[r], i);
        nxt[i] = old;
    }
}

// ---------------- Kernel 2: traverse list, accumulate moments, f64 Cholesky ----
// Writes a fused 32B record per node: {C0..C4, pos_r.x, pos_r.y, pad}
__global__ __launch_bounds__(256) void k_node(const float2* __restrict__ pos,
                                              const int* __restrict__ col,
                                              const int* __restrict__ head,
                                              const int* __restrict__ nxt,
                                              float* __restrict__ rec, int nN) {
    int n = blockIdx.x * blockDim.x + threadIdx.x;
    if (n >= nN) return;
    float2 pr = pos[n];
    float m[15];
    #pragma unroll
    for (int i = 0; i < 15; ++i) m[i] = 0.0f;

    int e = head[n];
    while (e >= 0) {
        int c = col[e];       // independent gathers: both issue before use
        int nx = nxt[e];
        float2 pc = pos[c];
        float x = pc.x - pr.x;
        float y = pc.y - pr.y;
        float xy = x * y, xx = x * x, yy = y * y;
        m[0]  += x * x;   m[1]  += x * y;   m[2]  += x * xy;  m[3]  += x * xx;  m[4]  += x * yy;
        m[5]  += y * y;   m[6]  += y * xy;  m[7]  += y * xx;  m[8]  += y * yy;
        m[9]  += xy * xy; m[10] += xy * xx; m[11] += xy * yy;
        m[12] += xx * xx; m[13] += xx * yy;
        m[14] += yy * yy;
        e = nx;
    }

    double A[5][5];
    {
        int idx = 0;
        #pragma unroll
        for (int i = 0; i < 5; ++i) {
            #pragma unroll
            for (int j = i; j < 5; ++j) {
                double v = (double)m[idx++];
                A[i][j] = v;
                A[j][i] = v;
            }
        }
    }
    #pragma unroll
    for (int i = 0; i < 5; ++i) A[i][i] += RIDGE;

    // Cholesky (static indices only)
    #pragma unroll
    for (int k = 0; k < 5; ++k) {
        double d = A[k][k];
        d = sqrt(fmax(d, 1e-300));
        A[k][k] = d;
        double inv = 1.0 / d;
        #pragma unroll
        for (int i = k + 1; i < 5; ++i) A[i][k] *= inv;
        #pragma unroll
        for (int j = k + 1; j < 5; ++j) {
            #pragma unroll
            for (int i = j; i < 5; ++i) A[i][j] -= A[i][k] * A[j][k];
        }
    }
    // b = [0,0,0,2,2]; L y = b
    double b[5] = {0.0, 0.0, 0.0, 2.0, 2.0};
    double y[5];
    #pragma unroll
    for (int i = 0; i < 5; ++i) {
        double sv = b[i];
        #pragma unroll
        for (int k = 0; k < 5; ++k) {
            if (k < i) sv -= A[i][k] * y[k];
        }
        y[i] = sv / A[i][i];
    }
    // L^T x = y
    double xs[5];
    #pragma unroll
    for (int ii = 4; ii >= 0; --ii) {
        double sv = y[ii];
        #pragma unroll
        for (int k = 0; k < 5; ++k) {
            if (k > ii) sv -= A[k][ii] * xs[k];
        }
        xs[ii] = sv / A[ii][ii];
    }

    float4* rb = (float4*)(rec + (size_t)n * 8);
    float4 r0 = make_float4((float)xs[0], (float)xs[1], (float)xs[2], (float)xs[3]);
    float4 r1 = make_float4((float)xs[4], pr.x, pr.y, 0.0f);
    rb[0] = r0;
    rb[1] = r1;
}

// ---------------- Kernel 3: per-edge weight = <C[row], H>, clipped ----------------
__global__ __launch_bounds__(256) void k_weights(const float2* __restrict__ pos,
                                                 const int* __restrict__ row,
                                                 const int* __restrict__ col,
                                                 const float* __restrict__ rec,
                                                 float* __restrict__ out,
                                                 int nE) {
    int e = blockIdx.x * blockDim.x + threadIdx.x;
    if (e >= nE) return;
    int r = row[e];
    int c = col[e];
    const float4* rb = (const float4*)(rec + (size_t)r * 8);
    float4 r0 = rb[0];               // C0..C3
    float4 r1 = rb[1];               // C4, pos_r.x, pos_r.y, pad
    float2 pc = pos[c];
    float x = pc.x - r1.y;
    float y = pc.y - r1.z;
    float w = r0.x * x + r0.y * y + r0.z * (x * y) + r0.w * (x * x) + r1.x * (y * y);
    w = fminf(fmaxf(w, -WLIM), WLIM);
    out[e] = w;
}

extern "C" void kernel_launch(void* const* d_in, const int* in_sizes, int n_in,
                              void* d_out, int out_size, void* d_ws, size_t ws_size,
                              hipStream_t stream) {
    const float2* pos = (const float2*)d_in[0];
    const int* ei = (const int*)d_in[1];
    const int nN = in_sizes[0] / 2;   // (N,2) f32
    const int nE = in_sizes[1] / 2;   // (2,E) int32
    const int* row = ei;
    const int* col = ei + nE;

    // workspace: head (nN ints) + rec (nN*8 floats) ~= 3.6MB
    int* head = (int*)d_ws;
    float* rec = (float*)(head + nN);

    // next[] lives in d_out (nE ints in nE floats); fully consumed by k_node
    // before k_weights overwrites d_out with the result.
    int* nxt = (int*)d_out;
    float* out = (float*)d_out;

    hipMemsetAsync(head, 0xFF, (size_t)nN * sizeof(int), stream);  // head = -1

    const int tb = 256;
    const int nE4 = nE / 4;
    const int bgrid = (nE4 + tb - 1) / tb;
    k_build<<<bgrid, tb, 0, stream>>>(row, head, nxt, nE4, nE);
    k_node<<<(nN + tb - 1) / tb, tb, 0, stream>>>(pos, col, head, nxt, rec, nN);
    k_weights<<<(nE + tb - 1) / tb, tb, 0, stream>>>(pos, row, col, rec, out, nE);
}